// Round 10
// baseline (9493.050 us; speedup 1.0000x reference)
//
#include <hip/hip_runtime.h>
#include <hip/hip_cooperative_groups.h>
#include <stdint.h>

namespace cg = cooperative_groups;

#define B_ 8192
#define T_ 21
#define F_ 3
#define U_ 512

typedef _Float16 f16x8 __attribute__((ext_vector_type(8)));
typedef float f32x4 __attribute__((ext_vector_type(4)));

__device__ __forceinline__ float fsigmoid(float x) { return 1.0f / (1.0f + __expf(-x)); }
__device__ __forceinline__ float ftanh_(float x) {
  float t = __expf(-2.0f * fabsf(x));
  float r = (1.0f - t) / (1.0f + t);
  return x < 0.0f ? -r : r;
}

__device__ __forceinline__ void gl_lds16(const void* g, void* l) {
  __builtin_amdgcn_global_load_lds((__attribute__((address_space(1))) void*)g,
                                   (__attribute__((address_space(3))) void*)l, 16, 0, 0);
}

// ---------------------------------------------------------------------------
// prep kernels (unchanged)
// ---------------------------------------------------------------------------
__global__ void prep_weights(const float* __restrict__ Wr, const float* __restrict__ wrnn,
                             const float* __restrict__ urnn, const float* __restrict__ kern,
                             const float* __restrict__ bias,
                             _Float16* __restrict__ WrT, _Float16* __restrict__ W2T,
                             float* __restrict__ Kp, float* __restrict__ bp) {
  size_t i = (size_t)blockIdx.x * 256 + threadIdx.x;
  if (i < (size_t)2048 * 512) {
    int p = (int)(i >> 9), k = (int)(i & 511);
    int orig = ((p >> 4) & 3) * 512 + ((p >> 6) << 4) + (p & 15);
    WrT[i] = (_Float16)Wr[(size_t)k * 2048 + orig];
  }
  if (i < (size_t)512 * 1024) {
    int n = (int)(i >> 10), k = (int)(i & 1023);
    float v = (k < 512) ? wrnn[(size_t)k * 512 + n] : urnn[(size_t)(k - 512) * 512 + n];
    W2T[i] = (_Float16)v;
  }
  if (i < 2048) {
    int p = (int)i;
    int orig = ((p >> 4) & 3) * 512 + ((p >> 6) << 4) + (p & 15);
    Kp[p] = kern[orig];
    Kp[2048 + p] = kern[2048 + orig];
    Kp[4096 + p] = kern[4096 + orig];
    bp[p] = bias[orig];
  }
}

__global__ void prep_wv(const float* __restrict__ wfc, const float* __restrict__ bfc,
                        const float* __restrict__ wout, const float* __restrict__ bout,
                        float* __restrict__ wv) {
  int u = blockIdx.x * 256 + threadIdx.x;
  if (u < 512) {
    float s = 0.0f;
    for (int k = 0; k < 32; ++k) s += wfc[u * 32 + k] * wout[k];
    wv[u] = s;
  }
  if (u == 0) {
    float s = 0.0f;
    for (int k = 0; k < 32; ++k) s += bfc[k] * wout[k];
    wv[512] = s + bout[0];
  }
}

__global__ void prep_mask(const int* __restrict__ lt, int* __restrict__ orow,
                          int* __restrict__ idxL, int* __restrict__ idxU,
                          int* __restrict__ Mpad) {
  const int t = blockIdx.x;
  const int tid = threadIdx.x;
  __shared__ int sh[1024];
  __shared__ int s_any, s_first;
  if (tid == 0) { s_any = 0; s_first = 0x7fffffff; }
  __syncthreads();
  const int base = tid * 8;
  const int* row = lt + (size_t)t * B_ + base;
  int bits = 0;
#pragma unroll
  for (int j = 0; j < 8; ++j) bits |= (row[j] == 1) << j;
  if (bits) atomicOr(&s_any, 1);
  __syncthreads();
  if (tid == 0 && !s_any) bits |= 1;  // force row 0 learned
  if (bits) atomicMin(&s_first, base + __ffs(bits) - 1);
  int lmax = -1;
#pragma unroll
  for (int j = 0; j < 8; ++j)
    if ((bits >> j) & 1) lmax = base + j;
  sh[tid] = lmax;
  __syncthreads();
  for (int off = 1; off < 1024; off <<= 1) {
    int v = (tid >= off) ? sh[tid - off] : -1;
    __syncthreads();
    if (v > sh[tid]) sh[tid] = v;
    __syncthreads();
  }
  const int prefix = (tid > 0) ? sh[tid - 1] : -1;
  __syncthreads();
  const int cnt = __popc(bits);
  sh[tid] = cnt;
  __syncthreads();
  for (int off = 1; off < 1024; off <<= 1) {
    int v = (tid >= off) ? sh[tid - off] : 0;
    __syncthreads();
    sh[tid] += v;
    __syncthreads();
  }
  const int excl = sh[tid] - cnt;
  const int total = sh[1023];
  const int first = s_first;
  int run = prefix, posL = excl, posU = base - excl;
  int* orp = orow + (size_t)t * B_ + base;
  int* ixL = idxL + (size_t)t * B_;
  int* ixU = idxU + (size_t)t * B_;
#pragma unroll
  for (int j = 0; j < 8; ++j) {
    if ((bits >> j) & 1) { ixL[posL++] = base + j; run = base + j; }
    else                 { ixU[posU++] = base + j; }
    orp[j] = (run < 0) ? first : run;
  }
  const int padded = (total + 127) & ~127;
  if (tid < padded - total) ixL[total + tid] = -1;
  const int totU = B_ - total;
  for (int i = totU + tid; i < B_; i += 1024) ixU[i] = -1;
  if (tid == 0) Mpad[t] = padded;
}

// ---------------------------------------------------------------------------
// GEMM tile: 128x128, BK=32, 4 waves (2x2), 16x16x32 f16 MFMA.
// r5 schedule: depth-2 prefetch, 3 LDS buffers, vmcnt ladder 8/4/0, 2 barriers.
// XOR-involution swizzle (r9): staging lane i -> row i>>2, k-block
// (i&3)^((row>>1)&3); frag read same XOR. Coalesced + conflict-free.
// ---------------------------------------------------------------------------
template <int MODE>
__device__ __forceinline__ void gemm_tile(
    _Float16 (*__restrict__ Ab)[4096], _Float16 (*__restrict__ Bb)[4096],
    const _Float16* __restrict__ A0, const _Float16* __restrict__ A1,
    const _Float16* __restrict__ Wt, const float* __restrict__ x,
    const float* __restrict__ Kp, const float* __restrict__ bp,
    _Float16* __restrict__ cbuf, _Float16* __restrict__ og,
    _Float16* __restrict__ hnew, const float* __restrict__ brnn,
    _Float16* __restrict__ rout, const int* __restrict__ idxL,
    int mBase, int nBase, int t) {
  constexpr int K = (MODE == 0) ? 512 : 1024;
  constexpr int NT = K / 32;
  const int tid = threadIdx.x;
  const int w = tid >> 6, l = tid & 63;
  const int wm = w >> 1, wn = w & 1;
  const int lr = l >> 2;
  const int kq = (((l & 3) ^ ((lr >> 1) & 3)) << 3);
  const int ch0 = w * 2, ch1 = w * 2 + 1;

  int ra0, ra1;
  if constexpr (MODE == 0) {
    int i0 = idxL[mBase + ch0 * 16 + lr];
    int i1 = idxL[mBase + ch1 * 16 + lr];
    ra0 = i0 < 0 ? 0 : i0;
    ra1 = i1 < 0 ? 0 : i1;
  } else {
    ra0 = mBase + ch0 * 16 + lr;
    ra1 = mBase + ch1 * 16 + lr;
  }

  auto STAGE = [&](int bb, int kt) {
    const int k0 = kt * 32;
    const _Float16* As = A0;
    int koff = k0;
    if constexpr (MODE == 1) {
      if (k0 >= 512) { As = A1; koff = k0 - 512; }
    }
    gl_lds16(As + (size_t)ra0 * 512 + koff + kq, (char*)Ab[bb] + ch0 * 1024);
    gl_lds16(As + (size_t)ra1 * 512 + koff + kq, (char*)Ab[bb] + ch1 * 1024);
    gl_lds16(Wt + (size_t)(nBase + ch0 * 16 + lr) * K + k0 + kq, (char*)Bb[bb] + ch0 * 1024);
    gl_lds16(Wt + (size_t)(nBase + ch1 * 16 + lr) * K + k0 + kq, (char*)Bb[bb] + ch1 * 1024);
  };

  f32x4 acc[4][4] = {};
  STAGE(0, 0);
  STAGE(1, 1);
  const int fm = l & 15, fk = l >> 4;
  const int fro = fm * 32 + ((fk ^ ((fm >> 1) & 3)) << 3);
#pragma unroll
  for (int kt = 0; kt < NT; ++kt) {
    if (kt + 2 < NT) {
      STAGE((kt + 2) % 3, kt + 2);
      asm volatile("s_waitcnt vmcnt(8)" ::: "memory");
    } else if (kt + 1 < NT) {
      asm volatile("s_waitcnt vmcnt(4)" ::: "memory");
    } else {
      asm volatile("s_waitcnt vmcnt(0)" ::: "memory");
    }
    __builtin_amdgcn_s_barrier();
    __builtin_amdgcn_sched_barrier(0);
    const int bb = kt % 3;
    f16x8 af[4], bf[4];
#pragma unroll
    for (int m = 0; m < 4; ++m)
      af[m] = *(const f16x8*)&Ab[bb][(wm * 64 + m * 16) * 32 + fro];
#pragma unroll
    for (int n = 0; n < 4; ++n)
      bf[n] = *(const f16x8*)&Bb[bb][(wn * 64 + n * 16) * 32 + fro];
    __builtin_amdgcn_s_setprio(1);
#pragma unroll
    for (int m = 0; m < 4; ++m)
#pragma unroll
      for (int n = 0; n < 4; ++n)
        acc[m][n] = __builtin_amdgcn_mfma_f32_16x16x32_f16(af[m], bf[n], acc[m][n], 0, 0, 0);
    __builtin_amdgcn_s_setprio(0);
    __builtin_amdgcn_sched_barrier(0);
    __builtin_amdgcn_s_barrier();
  }

  const int c_ = l & 15, rg = l >> 4;
  const int pB = nBase + wn * 64;
  if constexpr (MODE == 0) {
    const int u = (pB >> 6) * 16 + c_;
    float kf[4][3], bb4[4];
#pragma unroll
    for (int n = 0; n < 4; ++n) {
      int p = pB + n * 16 + c_;
      kf[n][0] = Kp[p]; kf[n][1] = Kp[2048 + p]; kf[n][2] = Kp[4096 + p];
      bb4[n] = bp[p];
    }
#pragma unroll
    for (int m = 0; m < 4; ++m) {
#pragma unroll
      for (int r = 0; r < 4; ++r) {
        int bi = idxL[mBase + wm * 64 + m * 16 + rg * 4 + r];
        if (bi < 0) continue;
        const float* xp = x + (size_t)bi * (T_ * F_) + t * F_;
        float x0 = xp[0], x1 = xp[1], x2 = xp[2];
        float zi = acc[m][0][r] + x0 * kf[0][0] + x1 * kf[0][1] + x2 * kf[0][2] + bb4[0];
        float zf = acc[m][1][r] + x0 * kf[1][0] + x1 * kf[1][1] + x2 * kf[1][2] + bb4[1];
        float zg = acc[m][2][r] + x0 * kf[2][0] + x1 * kf[2][1] + x2 * kf[2][2] + bb4[2];
        float zo = acc[m][3][r] + x0 * kf[3][0] + x1 * kf[3][1] + x2 * kf[3][2] + bb4[3];
        float ig = fsigmoid(zi), fg = fsigmoid(zf);
        float gg = ftanh_(zg), ogv = fsigmoid(zo);
        size_t ci = (size_t)bi * 512 + u;
        float cold = (float)cbuf[ci];
        float cnew = fg * cold + ig * gg;
        cbuf[ci] = (_Float16)cnew;
        og[ci] = (_Float16)ogv;
        hnew[ci] = (_Float16)(ogv * ftanh_(cnew));
      }
    }
  } else {
#pragma unroll
    for (int m = 0; m < 4; ++m)
#pragma unroll
      for (int n = 0; n < 4; ++n) {
        int uu = pB + n * 16 + c_;
        float bn = brnn[uu];
#pragma unroll
        for (int r = 0; r < 4; ++r) {
          int b = mBase + wm * 64 + m * 16 + rg * 4 + r;
          rout[(size_t)b * 512 + uu] = (_Float16)ftanh_(acc[m][n][r] + bn);
        }
      }
  }
}

// ---------------------------------------------------------------------------
// Persistent cooperative kernel: entire 21-step loop with grid syncs.
// Tile order per step: LSTM tiles [0,512), RNN tiles [512,768), LSTM
// overflow [768,..) -> doubled-up blocks do 16+16 iters = RNN's 32 pace.
// ---------------------------------------------------------------------------
__global__ __launch_bounds__(256, 3) void persist(
    const float* __restrict__ x, const float* __restrict__ Kp,
    const float* __restrict__ bp, const _Float16* __restrict__ WrT,
    const _Float16* __restrict__ W2T, _Float16* __restrict__ cbuf,
    _Float16* __restrict__ og, _Float16* __restrict__ h0,
    _Float16* __restrict__ h1, _Float16* __restrict__ r0,
    _Float16* __restrict__ r1, const float* __restrict__ brnn,
    const int* __restrict__ orow, const int* __restrict__ idxL,
    const int* __restrict__ idxU, const int* __restrict__ Mpad,
    const float* __restrict__ wv, float* __restrict__ out) {
  __shared__ __align__(16) _Float16 Ab[3][4096];
  __shared__ __align__(16) _Float16 Bb[3][4096];
  cg::grid_group grid = cg::this_grid();
  const int tid = threadIdx.x;
  _Float16* hb[2] = {h0, h1};
  _Float16* rb[2] = {r0, r1};

  for (int t = 0; t < T_; ++t) {
    const _Float16* hp = hb[t & 1];        // h(t-1)
    _Float16* hn = hb[(t + 1) & 1];        // h(t)
    const _Float16* rin = rb[(t + 1) & 1]; // r(t-2)
    _Float16* rot = rb[t & 1];             // r(t-1)
    const int* ixL = idxL + (size_t)t * B_;
    const int mT = Mpad[t] >> 7;           // LSTM m-tiles (32 or 33 typ.)
    const int nL = mT << 4;                // LSTM tiles total
    const int nTiles = 256 + nL;
    for (int idx = blockIdx.x; idx < nTiles; idx += gridDim.x) {
      int li;
      if (idx < 512) li = idx;
      else if (idx < 768) li = -1 - (idx - 512);   // RNN tile id in [0,256)
      else li = 512 + (idx - 768);                 // LSTM overflow
      if (li >= 0) {
        if (li < nL)
          gemm_tile<0>(Ab, Bb, hp, nullptr, WrT, x, Kp, bp, cbuf, og, hn,
                       nullptr, nullptr, ixL, (li % mT) * 128, (li / mT) * 128, t);
      } else {
        int ri = -1 - li;
        if (t >= 1)
          gemm_tile<1>(Ab, Bb, hp, rin, W2T, nullptr, nullptr, nullptr, nullptr,
                       nullptr, nullptr, brnn, rot, nullptr,
                       (ri >> 2) * 128, (ri & 3) * 128, t);
      }
    }
    __threadfence();
    grid.sync();
    __threadfence();
    // gather: unlearned rows of h(t)
    const int* ixU = idxU + (size_t)t * B_;
    const int* orw = orow + (size_t)t * B_;
    for (int g = blockIdx.x * 256 + tid; g < B_ * 64; g += gridDim.x * 256) {
      int b = ixU[g >> 6];
      if (b >= 0) {
        int u0 = (g & 63) << 3;
        int src = orw[b];
        f16x8 ov = *(const f16x8*)(og + (size_t)src * 512 + u0);
        f16x8 cv = *(const f16x8*)(cbuf + (size_t)b * 512 + u0);
        f16x8 hv;
#pragma unroll
        for (int j = 0; j < 8; ++j) hv[j] = (_Float16)((float)ov[j] * ftanh_((float)cv[j]));
        *(f16x8*)(hn + (size_t)b * 512 + u0) = hv;
      }
    }
    __threadfence();
    grid.sync();
    __threadfence();
  }
  // tail RNN: r(20) from h(20)=hb[T_&1], r(19)=rb[(T_+1)&1] -> rb[T_&1]
  {
    const _Float16* hT = hb[T_ & 1];
    const _Float16* rin = rb[(T_ + 1) & 1];
    _Float16* rot = rb[T_ & 1];
    for (int idx = blockIdx.x; idx < 256; idx += gridDim.x)
      gemm_tile<1>(Ab, Bb, hT, rin, W2T, nullptr, nullptr, nullptr, nullptr,
                   nullptr, nullptr, brnn, rot, nullptr,
                   (idx >> 2) * 128, (idx & 3) * 128, 0);
    __threadfence();
    grid.sync();
    __threadfence();
    // final fc: out[b] = dot(r(20)[b], wv) + wv[512]
    const int l = tid & 63;
    const int wid = (blockIdx.x * 256 + tid) >> 6;
    const int nW = (gridDim.x * 256) >> 6;
    const float4* wp = (const float4*)(wv + l * 8);
    float4 w0 = wp[0], w1 = wp[1];
    float wf[8] = {w0.x, w0.y, w0.z, w0.w, w1.x, w1.y, w1.z, w1.w};
    for (int gw = wid; gw < B_; gw += nW) {
      f16x8 rv = *(const f16x8*)(rot + (size_t)gw * 512 + l * 8);
      float s = 0.0f;
#pragma unroll
      for (int j = 0; j < 8; ++j) s += (float)rv[j] * wf[j];
      for (int o = 32; o; o >>= 1) s += __shfl_down(s, o);
      if (l == 0) out[gw] = s + wv[512];
    }
  }
}

// ---------------------------------------------------------------------------
// Fallback multi-launch kernels (r9-style host loop, r5-sched tile)
// ---------------------------------------------------------------------------
__global__ __launch_bounds__(256, 3) void fused_step(
    const _Float16* __restrict__ hprev, _Float16* __restrict__ hnew,
    const _Float16* __restrict__ rin, _Float16* __restrict__ rot,
    const _Float16* __restrict__ WrT, const _Float16* __restrict__ W2T,
    const float* __restrict__ x, const float* __restrict__ Kp,
    const float* __restrict__ bp, _Float16* __restrict__ cbuf,
    _Float16* __restrict__ og, const float* __restrict__ brnn,
    const int* __restrict__ idxL, const int* __restrict__ MpadP,
    int t, int yRnn) {
  __shared__ __align__(16) _Float16 Ab[3][4096];
  __shared__ __align__(16) _Float16 Bb[3][4096];
  if ((int)blockIdx.y < yRnn) {
    gemm_tile<1>(Ab, Bb, hprev, rin, W2T, nullptr, nullptr, nullptr, nullptr, nullptr,
                 nullptr, brnn, rot, nullptr, blockIdx.x * 128, blockIdx.y * 128, t);
  } else {
    if ((int)blockIdx.x * 128 >= *MpadP) return;
    gemm_tile<0>(Ab, Bb, hprev, nullptr, WrT, x, Kp, bp, cbuf, og, hnew, nullptr,
                 nullptr, idxL, blockIdx.x * 128, ((int)blockIdx.y - yRnn) * 128, t);
  }
}

__global__ __launch_bounds__(256, 3) void rnn_tail(
    const _Float16* __restrict__ h, const _Float16* __restrict__ rin,
    const _Float16* __restrict__ W2T, const float* __restrict__ brnn,
    _Float16* __restrict__ rot) {
  __shared__ __align__(16) _Float16 Ab[3][4096];
  __shared__ __align__(16) _Float16 Bb[3][4096];
  gemm_tile<1>(Ab, Bb, h, rin, W2T, nullptr, nullptr, nullptr, nullptr, nullptr,
               nullptr, brnn, rot, nullptr, blockIdx.x * 128, blockIdx.y * 128, 0);
}

__global__ void gather_h(const _Float16* __restrict__ og, const _Float16* __restrict__ cbuf,
                         const int* __restrict__ orow, const int* __restrict__ idxU,
                         _Float16* __restrict__ h) {
  int g = blockIdx.x * 256 + threadIdx.x;
  int b = idxU[g >> 6];
  if (b < 0) return;
  int u0 = (g & 63) << 3;
  int src = orow[b];
  f16x8 ov = *(const f16x8*)(og + (size_t)src * 512 + u0);
  f16x8 cv = *(const f16x8*)(cbuf + (size_t)b * 512 + u0);
  f16x8 hv;
#pragma unroll
  for (int j = 0; j < 8; ++j) hv[j] = (_Float16)((float)ov[j] * ftanh_((float)cv[j]));
  *(f16x8*)(h + (size_t)b * 512 + u0) = hv;
}

__global__ void final_fc(const _Float16* __restrict__ r, const float* __restrict__ wv,
                         float* __restrict__ out) {
  int gw = (blockIdx.x * 256 + threadIdx.x) >> 6;
  int l = threadIdx.x & 63;
  f16x8 rv = *(const f16x8*)(r + (size_t)gw * 512 + l * 8);
  const float4* wp = (const float4*)(wv + l * 8);
  float4 w0 = wp[0], w1 = wp[1];
  float wf[8] = {w0.x, w0.y, w0.z, w0.w, w1.x, w1.y, w1.z, w1.w};
  float s = 0.0f;
#pragma unroll
  for (int j = 0; j < 8; ++j) s += (float)rv[j] * wf[j];
  for (int o = 32; o; o >>= 1) s += __shfl_down(s, o);
  if (l == 0) out[gw] = s + wv[512];
}

extern "C" void kernel_launch(void* const* d_in, const int* in_sizes, int n_in,
                              void* d_out, int out_size, void* d_ws, size_t ws_size,
                              hipStream_t stream) {
  const float* x    = (const float*)d_in[0];
  const int*   lt   = (const int*)d_in[1];
  const float* kern = (const float*)d_in[2];
  const float* Wr   = (const float*)d_in[3];
  const float* bias = (const float*)d_in[4];
  const float* wrnn = (const float*)d_in[5];
  const float* urnn = (const float*)d_in[6];
  const float* brnn = (const float*)d_in[7];
  const float* wfc  = (const float*)d_in[8];
  const float* bfc  = (const float*)d_in[9];
  const float* wout = (const float*)d_in[10];
  const float* bout = (const float*)d_in[11];

  char* ws = (char*)d_ws;
  size_t off = 0;
  auto alloc = [&](size_t bytes) {
    void* p = ws + off;
    off = (off + bytes + 255) & ~(size_t)255;
    return p;
  };
  int*      orow = (int*)alloc((size_t)T_ * B_ * 4);
  int*      idxL = (int*)alloc((size_t)T_ * B_ * 4);
  int*      idxU = (int*)alloc((size_t)T_ * B_ * 4);
  int*      Mpad = (int*)alloc(T_ * 4);
  _Float16* cbuf = (_Float16*)alloc((size_t)B_ * U_ * 2);
  _Float16* h0   = (_Float16*)alloc((size_t)B_ * U_ * 2);
  _Float16* h1   = (_Float16*)alloc((size_t)B_ * U_ * 2);
  _Float16* r0   = (_Float16*)alloc((size_t)B_ * U_ * 2);
  _Float16* r1   = (_Float16*)alloc((size_t)B_ * U_ * 2);
  _Float16* og   = (_Float16*)alloc((size_t)B_ * U_ * 2);
  _Float16* WrT  = (_Float16*)alloc((size_t)2048 * 512 * 2);
  _Float16* W2T  = (_Float16*)alloc((size_t)512 * 1024 * 2);
  float*    Kp   = (float*)alloc(3 * 2048 * 4);
  float*    bp   = (float*)alloc(2048 * 4);
  float*    wv   = (float*)alloc(516 * 4);
  float*    outp = (float*)d_out;

  hipMemsetAsync(cbuf, 0, (size_t)B_ * U_ * 2, stream);
  hipMemsetAsync(h0, 0, (size_t)B_ * U_ * 2, stream);
  hipMemsetAsync(r0, 0, (size_t)B_ * U_ * 2, stream);

  prep_weights<<<4096, 256, 0, stream>>>(Wr, wrnn, urnn, kern, bias, WrT, W2T, Kp, bp);
  prep_wv<<<2, 256, 0, stream>>>(wfc, bfc, wout, bout, wv);
  prep_mask<<<T_, 1024, 0, stream>>>(lt, orow, idxL, idxU, Mpad);

  void* args[] = {(void*)&x, (void*)&Kp, (void*)&bp, (void*)&WrT, (void*)&W2T,
                  (void*)&cbuf, (void*)&og, (void*)&h0, (void*)&h1, (void*)&r0,
                  (void*)&r1, (void*)&brnn, (void*)&orow, (void*)&idxL,
                  (void*)&idxU, (void*)&Mpad, (void*)&wv, (void*)&outp};
  hipError_t err = hipLaunchCooperativeKernel((void*)persist, dim3(768), dim3(256),
                                              args, 0, stream);
  if (err != hipSuccess) {
    // fallback: proven multi-launch path
    _Float16* hbuf[2] = {h0, h1};
    _Float16* rin = r0;
    _Float16* rot = r1;
    fused_step<<<dim3(64, 16), 256, 0, stream>>>(h0, h1, nullptr, nullptr, WrT, W2T, x,
                                                 Kp, bp, cbuf, og, brnn, idxL, Mpad, 0, 0);
    gather_h<<<2048, 256, 0, stream>>>(og, cbuf, orow, idxU, h1);
    for (int t = 1; t < T_; ++t) {
      _Float16* hp = hbuf[t & 1];
      _Float16* hn = hbuf[(t + 1) & 1];
      fused_step<<<dim3(64, 20), 256, 0, stream>>>(hp, hn, rin, rot, WrT, W2T, x, Kp, bp,
                                                   cbuf, og, brnn,
                                                   idxL + (size_t)t * B_, Mpad + t, t, 4);
      _Float16* tmp = rin; rin = rot; rot = tmp;
      gather_h<<<2048, 256, 0, stream>>>(og, cbuf, orow + (size_t)t * B_,
                                         idxU + (size_t)t * B_, hn);
    }
    rnn_tail<<<dim3(64, 4), 256, 0, stream>>>(hbuf[T_ & 1], rin, W2T, brnn, rot);
    final_fc<<<2048, 256, 0, stream>>>(rot, wv, outp);
  }
}

// Round 11
// 1259.568 us; speedup vs baseline: 7.5367x; 7.5367x over previous
//
#include <hip/hip_runtime.h>
#include <stdint.h>

#define B_ 8192
#define T_ 21
#define F_ 3
#define U_ 512

typedef _Float16 f16x8 __attribute__((ext_vector_type(8)));
typedef float f32x4 __attribute__((ext_vector_type(4)));

__device__ __forceinline__ float fsigmoid(float x) { return 1.0f / (1.0f + __expf(-x)); }
__device__ __forceinline__ float ftanh_(float x) {
  float t = __expf(-2.0f * fabsf(x));
  float r = (1.0f - t) / (1.0f + t);
  return x < 0.0f ? -r : r;
}

__device__ __forceinline__ void gl_lds16(const void* g, void* l) {
  __builtin_amdgcn_global_load_lds((__attribute__((address_space(1))) void*)g,
                                   (__attribute__((address_space(3))) void*)l, 16, 0, 0);
}

// ---------------------------------------------------------------------------
// prep: transpose+pack weights to f16, pack kernel/bias with gate interleave
// packed col p for (gate g, unit u): p = 64*(u/16) + 16*g + (u%16)
// orig(p) = ((p>>4)&3)*512 + ((p>>6)<<4) + (p&15)
// ---------------------------------------------------------------------------
__global__ void prep_weights(const float* __restrict__ Wr, const float* __restrict__ wrnn,
                             const float* __restrict__ urnn, const float* __restrict__ kern,
                             const float* __restrict__ bias,
                             _Float16* __restrict__ WrT, _Float16* __restrict__ W2T,
                             float* __restrict__ Kp, float* __restrict__ bp) {
  size_t i = (size_t)blockIdx.x * 256 + threadIdx.x;
  if (i < (size_t)2048 * 512) {
    int p = (int)(i >> 9), k = (int)(i & 511);
    int orig = ((p >> 4) & 3) * 512 + ((p >> 6) << 4) + (p & 15);
    WrT[i] = (_Float16)Wr[(size_t)k * 2048 + orig];
  }
  if (i < (size_t)512 * 1024) {
    int n = (int)(i >> 10), k = (int)(i & 1023);
    float v = (k < 512) ? wrnn[(size_t)k * 512 + n] : urnn[(size_t)(k - 512) * 512 + n];
    W2T[i] = (_Float16)v;
  }
  if (i < 2048) {
    int p = (int)i;
    int orig = ((p >> 4) & 3) * 512 + ((p >> 6) << 4) + (p & 15);
    Kp[p] = kern[orig];
    Kp[2048 + p] = kern[2048 + orig];
    Kp[4096 + p] = kern[4096 + orig];
    bp[p] = bias[orig];
  }
}

__global__ void prep_wv(const float* __restrict__ wfc, const float* __restrict__ bfc,
                        const float* __restrict__ wout, const float* __restrict__ bout,
                        float* __restrict__ wv) {
  int u = blockIdx.x * 256 + threadIdx.x;
  if (u < 512) {
    float s = 0.0f;
    for (int k = 0; k < 32; ++k) s += wfc[u * 32 + k] * wout[k];
    wv[u] = s;
  }
  if (u == 0) {
    float s = 0.0f;
    for (int k = 0; k < 32; ++k) s += bfc[k] * wout[k];
    wv[512] = s + bout[0];
  }
}

// ---------------------------------------------------------------------------
// mask -> learned-row compaction (idxL, Mpad) + run lengths:
// runF[j] = #unlearned rows following learned j before next learned row;
// runB[j] = j if j is the FIRST learned row (backfill rows 0..j-1), else 0.
// one block (1024 thr) per timestep; each thread owns 8 consecutive rows.
// ---------------------------------------------------------------------------
__global__ void prep_mask(const int* __restrict__ lt, int* __restrict__ idxL,
                          int* __restrict__ runF, int* __restrict__ runB,
                          int* __restrict__ Mpad) {
  const int t = blockIdx.x;
  const int tid = threadIdx.x;
  __shared__ int sh[1024];
  __shared__ int s_any, s_first;
  if (tid == 0) { s_any = 0; s_first = 0x7fffffff; }
  __syncthreads();
  const int base = tid * 8;
  const int* row = lt + (size_t)t * B_ + base;
  int bits = 0;
#pragma unroll
  for (int j = 0; j < 8; ++j) bits |= (row[j] == 1) << j;
  if (bits) atomicOr(&s_any, 1);
  __syncthreads();
  if (tid == 0 && !s_any) bits |= 1;  // force row 0 learned
  if (bits) atomicMin(&s_first, base + __ffs(bits) - 1);
  // scan 1: prefix sum of counts -> compaction
  const int cnt = __popc(bits);
  sh[tid] = cnt;
  __syncthreads();
  for (int off = 1; off < 1024; off <<= 1) {
    int v = (tid >= off) ? sh[tid - off] : 0;
    __syncthreads();
    sh[tid] += v;
    __syncthreads();
  }
  const int excl = sh[tid] - cnt;
  const int total = sh[1023];
  __syncthreads();
  // scan 2: suffix-min of firstL -> next learned row after my range
  const int firstL = bits ? (base + __ffs(bits) - 1) : 0x7fffffff;
  sh[tid] = firstL;
  __syncthreads();
  for (int off = 1; off < 1024; off <<= 1) {
    int v = (tid + off < 1024) ? sh[tid + off] : 0x7fffffff;
    __syncthreads();
    if (v < sh[tid]) sh[tid] = v;
    __syncthreads();
  }
  const int nxtOut = (tid < 1023) ? sh[tid + 1] : 0x7fffffff;
  const int first = s_first;
  // emit compacted indices + run lengths (walk high -> low for runF)
  int* ixL = idxL + (size_t)t * B_;
  int* rF = runF + (size_t)t * B_;
  int* rB = runB + (size_t)t * B_;
  int pos = excl;
#pragma unroll
  for (int j = 0; j < 8; ++j)
    if ((bits >> j) & 1) ixL[pos++] = base + j;
  int nl = nxtOut;
#pragma unroll
  for (int j = 7; j >= 0; --j)
    if ((bits >> j) & 1) {
      int r0 = base + j;
      rF[r0] = ((nl == 0x7fffffff) ? (B_ - 1) : (nl - 1)) - r0;
      rB[r0] = (r0 == first) ? r0 : 0;
      nl = r0;
    }
  const int padded = (total + 127) & ~127;
  if (tid < padded - total) ixL[total + tid] = -1;
  if (tid == 0) Mpad[t] = padded;
}

// ---------------------------------------------------------------------------
// GEMM tile: 128x128, BK=32, 4 waves (2x2), 16x16x32 f16 MFMA.
// 3 LDS buffers, depth-2 prefetch, counted vmcnt(4)/(0), ONE barrier/iter
// (safe: STAGE((kt+2)%3) issued after barrier(kt); all waves passed
// barrier(kt) only after consuming buf[(kt-1)%3] == buf[(kt+2)%3]).
// XOR-involution swizzle: staging lane i -> row i>>2, k-block
// (i&3)^((row>>1)&3); frag read same XOR -> coalesced + conflict-free.
// MODE 0: LSTM on gathered learned rows; epilogue: gates, fp16-c update,
//         h=o*tanh(c) for learned row + its run of unlearned rows
//         (forward-fill) and backfill before the first learned row.
// MODE 1: RNN z=[h|r]@W2T^T -> tanh -> rout.
// ---------------------------------------------------------------------------
template <int MODE>
__device__ __forceinline__ void gemm_tile(
    _Float16 (*__restrict__ Ab)[4096], _Float16 (*__restrict__ Bb)[4096],
    const _Float16* __restrict__ A0, const _Float16* __restrict__ A1,
    const _Float16* __restrict__ Wt, const float* __restrict__ x,
    const float* __restrict__ Kp, const float* __restrict__ bp,
    _Float16* __restrict__ cbuf, _Float16* __restrict__ hnew,
    const float* __restrict__ brnn, _Float16* __restrict__ rout,
    const int* __restrict__ idxL, const int* __restrict__ rF,
    const int* __restrict__ rB, int mBase, int nBase, int t) {
  constexpr int K = (MODE == 0) ? 512 : 1024;
  constexpr int NT = K / 32;
  const int tid = threadIdx.x;
  const int w = tid >> 6, l = tid & 63;
  const int wm = w >> 1, wn = w & 1;
  const int lr = l >> 2;
  const int kq = (((l & 3) ^ ((lr >> 1) & 3)) << 3);
  const int ch0 = w * 2, ch1 = w * 2 + 1;

  int ra0, ra1;
  if constexpr (MODE == 0) {
    int i0 = idxL[mBase + ch0 * 16 + lr];
    int i1 = idxL[mBase + ch1 * 16 + lr];
    ra0 = i0 < 0 ? 0 : i0;
    ra1 = i1 < 0 ? 0 : i1;
  } else {
    ra0 = mBase + ch0 * 16 + lr;
    ra1 = mBase + ch1 * 16 + lr;
  }

  auto STAGE = [&](int bb, int kt) {
    const int k0 = kt * 32;
    const _Float16* As = A0;
    int koff = k0;
    if constexpr (MODE == 1) {
      if (k0 >= 512) { As = A1; koff = k0 - 512; }
    }
    gl_lds16(As + (size_t)ra0 * 512 + koff + kq, (char*)Ab[bb] + ch0 * 1024);
    gl_lds16(As + (size_t)ra1 * 512 + koff + kq, (char*)Ab[bb] + ch1 * 1024);
    gl_lds16(Wt + (size_t)(nBase + ch0 * 16 + lr) * K + k0 + kq, (char*)Bb[bb] + ch0 * 1024);
    gl_lds16(Wt + (size_t)(nBase + ch1 * 16 + lr) * K + k0 + kq, (char*)Bb[bb] + ch1 * 1024);
  };

  f32x4 acc[4][4] = {};
  STAGE(0, 0);
  STAGE(1, 1);
  const int fm = l & 15, fk = l >> 4;
  const int fro = fm * 32 + ((fk ^ ((fm >> 1) & 3)) << 3);
  for (int kt = 0; kt < NT; ++kt) {
    if (kt + 1 < NT) {
      asm volatile("s_waitcnt vmcnt(4)" ::: "memory");
    } else {
      asm volatile("s_waitcnt vmcnt(0)" ::: "memory");
    }
    __builtin_amdgcn_s_barrier();
    __builtin_amdgcn_sched_barrier(0);
    const int bb = kt % 3;
    f16x8 af[4], bf[4];
#pragma unroll
    for (int m = 0; m < 4; ++m)
      af[m] = *(const f16x8*)&Ab[bb][(wm * 64 + m * 16) * 32 + fro];
#pragma unroll
    for (int n = 0; n < 4; ++n)
      bf[n] = *(const f16x8*)&Bb[bb][(wn * 64 + n * 16) * 32 + fro];
    __builtin_amdgcn_s_setprio(1);
#pragma unroll
    for (int m = 0; m < 4; ++m)
#pragma unroll
      for (int n = 0; n < 4; ++n)
        acc[m][n] = __builtin_amdgcn_mfma_f32_16x16x32_f16(af[m], bf[n], acc[m][n], 0, 0, 0);
    __builtin_amdgcn_s_setprio(0);
    __builtin_amdgcn_sched_barrier(0);
    if (kt + 2 < NT) STAGE((kt + 2) % 3, kt + 2);
  }

  const int c_ = l & 15, rg = l >> 4;
  const int pB = nBase + wn * 64;
  if constexpr (MODE == 0) {
    const int u = (pB >> 6) * 16 + c_;
    float kf[4][3], bb4[4];
#pragma unroll
    for (int n = 0; n < 4; ++n) {
      int p = pB + n * 16 + c_;
      kf[n][0] = Kp[p]; kf[n][1] = Kp[2048 + p]; kf[n][2] = Kp[4096 + p];
      bb4[n] = bp[p];
    }
#pragma unroll
    for (int m = 0; m < 4; ++m) {
#pragma unroll
      for (int r = 0; r < 4; ++r) {
        int bi = idxL[mBase + wm * 64 + m * 16 + rg * 4 + r];
        if (bi < 0) continue;
        const float* xp = x + (size_t)bi * (T_ * F_) + t * F_;
        float x0 = xp[0], x1 = xp[1], x2 = xp[2];
        float zi = acc[m][0][r] + x0 * kf[0][0] + x1 * kf[0][1] + x2 * kf[0][2] + bb4[0];
        float zf = acc[m][1][r] + x0 * kf[1][0] + x1 * kf[1][1] + x2 * kf[1][2] + bb4[1];
        float zg = acc[m][2][r] + x0 * kf[2][0] + x1 * kf[2][1] + x2 * kf[2][2] + bb4[2];
        float zo = acc[m][3][r] + x0 * kf[3][0] + x1 * kf[3][1] + x2 * kf[3][2] + bb4[3];
        float ig = fsigmoid(zi), fg = fsigmoid(zf);
        float gg = ftanh_(zg), ogv = fsigmoid(zo);
        size_t ci = (size_t)bi * 512 + u;
        float cold = (float)cbuf[ci];
        float cnew = fg * cold + ig * gg;  // all rows here are learned
        cbuf[ci] = (_Float16)cnew;
        hnew[ci] = (_Float16)(ogv * ftanh_(cnew));
        // forward-fill this learned row's o over its run of unlearned rows
        int nf = rF[bi];
        for (int k2 = 1; k2 <= nf; ++k2) {
          size_t c2 = ci + (size_t)k2 * 512;
          hnew[c2] = (_Float16)(ogv * ftanh_((float)cbuf[c2]));
        }
        // backfill rows before the first learned row (rB nonzero only there)
        int nb = rB[bi];
        for (int k2 = 1; k2 <= nb; ++k2) {
          size_t c2 = ci - (size_t)k2 * 512;
          hnew[c2] = (_Float16)(ogv * ftanh_((float)cbuf[c2]));
        }
      }
    }
  } else {
#pragma unroll
    for (int m = 0; m < 4; ++m)
#pragma unroll
      for (int n = 0; n < 4; ++n) {
        int uu = pB + n * 16 + c_;
        float bn = brnn[uu];
#pragma unroll
        for (int r = 0; r < 4; ++r) {
          int b = mBase + wm * 64 + m * 16 + rg * 4 + r;
          rout[(size_t)b * 512 + uu] = (_Float16)ftanh_(acc[m][n][r] + bn);
        }
      }
  }
}

// Fused dispatch: y < yRnn -> RNN (first: 2x K, long pole); y >= yRnn ->
// LSTM(t) on learned rows. Both read h(t-1); independent.
__global__ __launch_bounds__(256, 3) void fused_step(
    const _Float16* __restrict__ hprev, _Float16* __restrict__ hnew,
    const _Float16* __restrict__ rin, _Float16* __restrict__ rot,
    const _Float16* __restrict__ WrT, const _Float16* __restrict__ W2T,
    const float* __restrict__ x, const float* __restrict__ Kp,
    const float* __restrict__ bp, _Float16* __restrict__ cbuf,
    const float* __restrict__ brnn, const int* __restrict__ idxL,
    const int* __restrict__ rF, const int* __restrict__ rB,
    const int* __restrict__ MpadP, int t, int yRnn) {
  __shared__ __align__(16) _Float16 Ab[3][4096];
  __shared__ __align__(16) _Float16 Bb[3][4096];
  if ((int)blockIdx.y < yRnn) {
    gemm_tile<1>(Ab, Bb, hprev, rin, W2T, nullptr, nullptr, nullptr, nullptr,
                 nullptr, brnn, rot, nullptr, nullptr, nullptr,
                 blockIdx.x * 128, blockIdx.y * 128, t);
  } else {
    if ((int)blockIdx.x * 128 >= *MpadP) return;
    gemm_tile<0>(Ab, Bb, hprev, nullptr, WrT, x, Kp, bp, cbuf, hnew,
                 nullptr, nullptr, idxL, rF, rB,
                 blockIdx.x * 128, ((int)blockIdx.y - yRnn) * 128, t);
  }
}

__global__ __launch_bounds__(256, 3) void rnn_tail(
    const _Float16* __restrict__ h, const _Float16* __restrict__ rin,
    const _Float16* __restrict__ W2T, const float* __restrict__ brnn,
    _Float16* __restrict__ rot) {
  __shared__ __align__(16) _Float16 Ab[3][4096];
  __shared__ __align__(16) _Float16 Bb[3][4096];
  gemm_tile<1>(Ab, Bb, h, rin, W2T, nullptr, nullptr, nullptr, nullptr,
               nullptr, brnn, rot, nullptr, nullptr, nullptr,
               blockIdx.x * 128, blockIdx.y * 128, 0);
}

// out[b] = dot(r[b], wv) + c0  (one wave per row), fp32 output
__global__ void final_fc(const _Float16* __restrict__ r, const float* __restrict__ wv,
                         float* __restrict__ out) {
  int gw = (blockIdx.x * 256 + threadIdx.x) >> 6;
  int l = threadIdx.x & 63;
  f16x8 rv = *(const f16x8*)(r + (size_t)gw * 512 + l * 8);
  const float4* wp = (const float4*)(wv + l * 8);
  float4 w0 = wp[0], w1 = wp[1];
  float wf[8] = {w0.x, w0.y, w0.z, w0.w, w1.x, w1.y, w1.z, w1.w};
  float s = 0.0f;
#pragma unroll
  for (int j = 0; j < 8; ++j) s += (float)rv[j] * wf[j];
  for (int o = 32; o; o >>= 1) s += __shfl_down(s, o);
  if (l == 0) out[gw] = s + wv[512];
}

extern "C" void kernel_launch(void* const* d_in, const int* in_sizes, int n_in,
                              void* d_out, int out_size, void* d_ws, size_t ws_size,
                              hipStream_t stream) {
  const float* x    = (const float*)d_in[0];
  const int*   lt   = (const int*)d_in[1];
  const float* kern = (const float*)d_in[2];
  const float* Wr   = (const float*)d_in[3];
  const float* bias = (const float*)d_in[4];
  const float* wrnn = (const float*)d_in[5];
  const float* urnn = (const float*)d_in[6];
  const float* brnn = (const float*)d_in[7];
  const float* wfc  = (const float*)d_in[8];
  const float* bfc  = (const float*)d_in[9];
  const float* wout = (const float*)d_in[10];
  const float* bout = (const float*)d_in[11];

  char* ws = (char*)d_ws;
  size_t off = 0;
  auto alloc = [&](size_t bytes) {
    void* p = ws + off;
    off = (off + bytes + 255) & ~(size_t)255;
    return p;
  };
  int*      idxL = (int*)alloc((size_t)T_ * B_ * 4);
  int*      runF = (int*)alloc((size_t)T_ * B_ * 4);
  int*      runB = (int*)alloc((size_t)T_ * B_ * 4);
  int*      Mpad = (int*)alloc(T_ * 4);
  _Float16* cbuf = (_Float16*)alloc((size_t)B_ * U_ * 2);
  _Float16* h0   = (_Float16*)alloc((size_t)B_ * U_ * 2);
  _Float16* h1   = (_Float16*)alloc((size_t)B_ * U_ * 2);
  _Float16* r0   = (_Float16*)alloc((size_t)B_ * U_ * 2);
  _Float16* r1   = (_Float16*)alloc((size_t)B_ * U_ * 2);
  _Float16* WrT  = (_Float16*)alloc((size_t)2048 * 512 * 2);
  _Float16* W2T  = (_Float16*)alloc((size_t)512 * 1024 * 2);
  float*    Kp   = (float*)alloc(3 * 2048 * 4);
  float*    bp   = (float*)alloc(2048 * 4);
  float*    wv   = (float*)alloc(516 * 4);

  hipMemsetAsync(cbuf, 0, (size_t)B_ * U_ * 2, stream);
  hipMemsetAsync(h0, 0, (size_t)B_ * U_ * 2, stream);
  hipMemsetAsync(r0, 0, (size_t)B_ * U_ * 2, stream);

  prep_weights<<<4096, 256, 0, stream>>>(Wr, wrnn, urnn, kern, bias, WrT, W2T, Kp, bp);
  prep_wv<<<2, 256, 0, stream>>>(wfc, bfc, wout, bout, wv);
  prep_mask<<<T_, 1024, 0, stream>>>(lt, idxL, runF, runB, Mpad);

  _Float16* hbuf[2] = {h0, h1};
  _Float16* rin = r0;
  _Float16* rot = r1;
  // step t reads hbuf[t&1] (= h(t-1)), writes hbuf[(t+1)&1] (= h(t));
  // h(t) is COMPLETE (learned + run-filled unlearned) after fused_step(t).
  fused_step<<<dim3(64, 16), 256, 0, stream>>>(h0, h1, nullptr, nullptr, WrT, W2T, x,
                                               Kp, bp, cbuf, brnn, idxL, runF, runB,
                                               Mpad, 0, 0);
  for (int t = 1; t < T_; ++t) {
    _Float16* hp = hbuf[t & 1];
    _Float16* hn = hbuf[(t + 1) & 1];
    fused_step<<<dim3(64, 20), 256, 0, stream>>>(hp, hn, rin, rot, WrT, W2T, x, Kp, bp,
                                                 cbuf, brnn, idxL + (size_t)t * B_,
                                                 runF + (size_t)t * B_,
                                                 runB + (size_t)t * B_,
                                                 Mpad + t, t, 4);
    _Float16* tmp = rin; rin = rot; rot = tmp;  // rin now holds r(t-1)
  }
  // tail: r(20) from h(20) in hbuf[T_&1], r(19) = rin
  rnn_tail<<<dim3(64, 4), 256, 0, stream>>>(hbuf[T_ & 1], rin, W2T, brnn, rot);
  final_fc<<<2048, 256, 0, stream>>>(rot, wv, (float*)d_out);
}

// Round 12
// 1031.516 us; speedup vs baseline: 9.2030x; 1.2211x over previous
//
#include <hip/hip_runtime.h>
#include <stdint.h>

#define B_ 8192
#define T_ 21
#define F_ 3
#define U_ 512

typedef _Float16 f16x8 __attribute__((ext_vector_type(8)));
typedef float f32x4 __attribute__((ext_vector_type(4)));

__device__ __forceinline__ float fsigmoid(float x) { return 1.0f / (1.0f + __expf(-x)); }
__device__ __forceinline__ float ftanh_(float x) {
  float t = __expf(-2.0f * fabsf(x));
  float r = (1.0f - t) / (1.0f + t);
  return x < 0.0f ? -r : r;
}

__device__ __forceinline__ void gl_lds16(const void* g, void* l) {
  __builtin_amdgcn_global_load_lds((__attribute__((address_space(1))) void*)g,
                                   (__attribute__((address_space(3))) void*)l, 16, 0, 0);
}

// ---------------------------------------------------------------------------
// prep: transpose+pack weights to f16, pack kernel/bias with gate interleave
// packed col p for (gate g, unit u): p = 64*(u/16) + 16*g + (u%16)
// orig(p) = ((p>>4)&3)*512 + ((p>>6)<<4) + (p&15)
// ---------------------------------------------------------------------------
__global__ void prep_weights(const float* __restrict__ Wr, const float* __restrict__ wrnn,
                             const float* __restrict__ urnn, const float* __restrict__ kern,
                             const float* __restrict__ bias,
                             _Float16* __restrict__ WrT, _Float16* __restrict__ W2T,
                             float* __restrict__ Kp, float* __restrict__ bp) {
  size_t i = (size_t)blockIdx.x * 256 + threadIdx.x;
  if (i < (size_t)2048 * 512) {
    int p = (int)(i >> 9), k = (int)(i & 511);
    int orig = ((p >> 4) & 3) * 512 + ((p >> 6) << 4) + (p & 15);
    WrT[i] = (_Float16)Wr[(size_t)k * 2048 + orig];
  }
  if (i < (size_t)512 * 1024) {
    int n = (int)(i >> 10), k = (int)(i & 1023);
    float v = (k < 512) ? wrnn[(size_t)k * 512 + n] : urnn[(size_t)(k - 512) * 512 + n];
    W2T[i] = (_Float16)v;
  }
  if (i < 2048) {
    int p = (int)i;
    int orig = ((p >> 4) & 3) * 512 + ((p >> 6) << 4) + (p & 15);
    Kp[p] = kern[orig];
    Kp[2048 + p] = kern[2048 + orig];
    Kp[4096 + p] = kern[4096 + orig];
    bp[p] = bias[orig];
  }
}

__global__ void prep_wv(const float* __restrict__ wfc, const float* __restrict__ bfc,
                        const float* __restrict__ wout, const float* __restrict__ bout,
                        float* __restrict__ wv) {
  int u = blockIdx.x * 256 + threadIdx.x;
  if (u < 512) {
    float s = 0.0f;
    for (int k = 0; k < 32; ++k) s += wfc[u * 32 + k] * wout[k];
    wv[u] = s;
  }
  if (u == 0) {
    float s = 0.0f;
    for (int k = 0; k < 32; ++k) s += bfc[k] * wout[k];
    wv[512] = s + bout[0];
  }
}

// ---------------------------------------------------------------------------
// mask + o_idx + learned/unlearned row compaction (r9-proven version).
// ---------------------------------------------------------------------------
__global__ void prep_mask(const int* __restrict__ lt, int* __restrict__ orow,
                          int* __restrict__ idxL, int* __restrict__ idxU,
                          int* __restrict__ Mpad) {
  const int t = blockIdx.x;
  const int tid = threadIdx.x;
  __shared__ int sh[1024];
  __shared__ int s_any, s_first;
  if (tid == 0) { s_any = 0; s_first = 0x7fffffff; }
  __syncthreads();
  const int base = tid * 8;
  const int* row = lt + (size_t)t * B_ + base;
  int bits = 0;
#pragma unroll
  for (int j = 0; j < 8; ++j) bits |= (row[j] == 1) << j;
  if (bits) atomicOr(&s_any, 1);
  __syncthreads();
  if (tid == 0 && !s_any) bits |= 1;  // force row 0 learned
  if (bits) atomicMin(&s_first, base + __ffs(bits) - 1);
  int lmax = -1;
#pragma unroll
  for (int j = 0; j < 8; ++j)
    if ((bits >> j) & 1) lmax = base + j;
  sh[tid] = lmax;
  __syncthreads();
  for (int off = 1; off < 1024; off <<= 1) {
    int v = (tid >= off) ? sh[tid - off] : -1;
    __syncthreads();
    if (v > sh[tid]) sh[tid] = v;
    __syncthreads();
  }
  const int prefix = (tid > 0) ? sh[tid - 1] : -1;
  __syncthreads();
  const int cnt = __popc(bits);
  sh[tid] = cnt;
  __syncthreads();
  for (int off = 1; off < 1024; off <<= 1) {
    int v = (tid >= off) ? sh[tid - off] : 0;
    __syncthreads();
    sh[tid] += v;
    __syncthreads();
  }
  const int excl = sh[tid] - cnt;
  const int total = sh[1023];
  const int first = s_first;
  int run = prefix, posL = excl, posU = base - excl;
  int* orp = orow + (size_t)t * B_ + base;
  int* ixL = idxL + (size_t)t * B_;
  int* ixU = idxU + (size_t)t * B_;
#pragma unroll
  for (int j = 0; j < 8; ++j) {
    if ((bits >> j) & 1) { ixL[posL++] = base + j; run = base + j; }
    else                 { ixU[posU++] = base + j; }
    orp[j] = (run < 0) ? first : run;
  }
  const int padded = (total + 127) & ~127;
  if (tid < padded - total) ixL[total + tid] = -1;
  const int totU = B_ - total;
  for (int i = totU + tid; i < B_; i += 1024) ixU[i] = -1;
  if (tid == 0) Mpad[t] = padded;
}

// ---------------------------------------------------------------------------
// GEMM tiles. Shared schedule: 3 LDS buffers, depth-2 prefetch, counted
// vmcnt (never 0 mid-loop), ONE barrier/iter (safe: each wave's own vmcnt
// wait precedes its barrier arrival, so post-barrier all stage-kt loads are
// globally complete; STAGE((kt+2)%3) after barrier(kt) cannot collide with
// buf[(kt-1)%3] readers). XOR-involution swizzle: staging lane i -> row
// i>>2, k-block (i&3)^((row>>1)&3); frag read same XOR -> coalesced 64B per
// 4-lane group AND <=2-way LDS bank aliasing.
// MODE 0: LSTM 128x128 tile, 2x2 waves, K=512, gathered learned rows;
//         epilogue: gates, fp16-c update, og + h(learned) writes.
// MODE 1: RNN 128x64 tile, 4x1 waves (wave w: rows w*32..+32, all 64 cols),
//         K=1024 over [h|r]; per-wave staging 2 A-chunks + 1 B-chunk;
//         epilogue: tanh(+b_rnn) -> rout. Work/block == MODE 0 (balanced).
// ---------------------------------------------------------------------------
template <int MODE>
__device__ __forceinline__ void gemm_tile(
    _Float16 (*__restrict__ Ab)[4096], _Float16 (*__restrict__ Bb)[4096],
    const _Float16* __restrict__ A0, const _Float16* __restrict__ A1,
    const _Float16* __restrict__ Wt, const float* __restrict__ x,
    const float* __restrict__ Kp, const float* __restrict__ bp,
    _Float16* __restrict__ cbuf, _Float16* __restrict__ og,
    _Float16* __restrict__ hnew, const float* __restrict__ brnn,
    _Float16* __restrict__ rout, const int* __restrict__ idxL,
    int mBase, int nBase, int t) {
  constexpr int K = (MODE == 0) ? 512 : 1024;
  constexpr int NT = K / 32;
  const int tid = threadIdx.x;
  const int w = tid >> 6, l = tid & 63;
  const int lr = l >> 2;
  const int kq = (((l & 3) ^ ((lr >> 1) & 3)) << 3);
  const int ch0 = w * 2, ch1 = w * 2 + 1;

  int ra0, ra1;
  if constexpr (MODE == 0) {
    int i0 = idxL[mBase + ch0 * 16 + lr];
    int i1 = idxL[mBase + ch1 * 16 + lr];
    ra0 = i0 < 0 ? 0 : i0;
    ra1 = i1 < 0 ? 0 : i1;
  } else {
    ra0 = mBase + ch0 * 16 + lr;
    ra1 = mBase + ch1 * 16 + lr;
  }

  auto STAGE = [&](int bb, int kt) {
    const int k0 = kt * 32;
    const _Float16* As = A0;
    int koff = k0;
    if constexpr (MODE == 1) {
      if (k0 >= 512) { As = A1; koff = k0 - 512; }
    }
    gl_lds16(As + (size_t)ra0 * 512 + koff + kq, (char*)Ab[bb] + ch0 * 1024);
    gl_lds16(As + (size_t)ra1 * 512 + koff + kq, (char*)Ab[bb] + ch1 * 1024);
    if constexpr (MODE == 0) {
      gl_lds16(Wt + (size_t)(nBase + ch0 * 16 + lr) * K + k0 + kq, (char*)Bb[bb] + ch0 * 1024);
      gl_lds16(Wt + (size_t)(nBase + ch1 * 16 + lr) * K + k0 + kq, (char*)Bb[bb] + ch1 * 1024);
    } else {
      // 64 B-rows total: wave w stages chunk w (rows nBase+16w..+16)
      gl_lds16(Wt + (size_t)(nBase + w * 16 + lr) * K + k0 + kq, (char*)Bb[bb] + w * 1024);
    }
  };

  constexpr int MR = (MODE == 0) ? 4 : 2;  // m-frags per wave
  constexpr int NR = 4;                    // n-frags per wave
  f32x4 acc[MR][NR] = {};
  STAGE(0, 0);
  STAGE(1, 1);
  const int fm = l & 15, fk = l >> 4;
  const int fro = fm * 32 + ((fk ^ ((fm >> 1) & 3)) << 3);
  const int wm = (MODE == 0) ? (w >> 1) : w;
  const int wn = (MODE == 0) ? (w & 1) : 0;
  for (int kt = 0; kt < NT; ++kt) {
    if (kt + 1 < NT) {
      if constexpr (MODE == 0)
        asm volatile("s_waitcnt vmcnt(4)" ::: "memory");
      else
        asm volatile("s_waitcnt vmcnt(3)" ::: "memory");
    } else {
      asm volatile("s_waitcnt vmcnt(0)" ::: "memory");
    }
    __builtin_amdgcn_s_barrier();
    __builtin_amdgcn_sched_barrier(0);
    const int bb = kt % 3;
    f16x8 af[MR], bf[NR];
#pragma unroll
    for (int m = 0; m < MR; ++m)
      af[m] = *(const f16x8*)&Ab[bb][((MODE == 0 ? wm * 64 : w * 32) + m * 16) * 32 + fro];
#pragma unroll
    for (int n = 0; n < NR; ++n)
      bf[n] = *(const f16x8*)&Bb[bb][((MODE == 0 ? wn * 64 : 0) + n * 16) * 32 + fro];
    __builtin_amdgcn_s_setprio(1);
#pragma unroll
    for (int m = 0; m < MR; ++m)
#pragma unroll
      for (int n = 0; n < NR; ++n)
        acc[m][n] = __builtin_amdgcn_mfma_f32_16x16x32_f16(af[m], bf[n], acc[m][n], 0, 0, 0);
    __builtin_amdgcn_s_setprio(0);
    __builtin_amdgcn_sched_barrier(0);
    if (kt + 2 < NT) STAGE((kt + 2) % 3, kt + 2);
  }

  const int c_ = l & 15, rg = l >> 4;
  if constexpr (MODE == 0) {
    const int pB = nBase + wn * 64;
    const int u = (pB >> 6) * 16 + c_;
    float kf[4][3], bb4[4];
#pragma unroll
    for (int n = 0; n < 4; ++n) {
      int p = pB + n * 16 + c_;
      kf[n][0] = Kp[p]; kf[n][1] = Kp[2048 + p]; kf[n][2] = Kp[4096 + p];
      bb4[n] = bp[p];
    }
#pragma unroll
    for (int m = 0; m < 4; ++m) {
#pragma unroll
      for (int r = 0; r < 4; ++r) {
        int bi = idxL[mBase + wm * 64 + m * 16 + rg * 4 + r];
        if (bi < 0) continue;
        const float* xp = x + (size_t)bi * (T_ * F_) + t * F_;
        float x0 = xp[0], x1 = xp[1], x2 = xp[2];
        float zi = acc[m][0][r] + x0 * kf[0][0] + x1 * kf[0][1] + x2 * kf[0][2] + bb4[0];
        float zf = acc[m][1][r] + x0 * kf[1][0] + x1 * kf[1][1] + x2 * kf[1][2] + bb4[1];
        float zg = acc[m][2][r] + x0 * kf[2][0] + x1 * kf[2][1] + x2 * kf[2][2] + bb4[2];
        float zo = acc[m][3][r] + x0 * kf[3][0] + x1 * kf[3][1] + x2 * kf[3][2] + bb4[3];
        float ig = fsigmoid(zi), fg = fsigmoid(zf);
        float gg = ftanh_(zg), ogv = fsigmoid(zo);
        size_t ci = (size_t)bi * 512 + u;
        float cold = (float)cbuf[ci];
        float cnew = fg * cold + ig * gg;  // all rows here are learned
        cbuf[ci] = (_Float16)cnew;
        og[ci] = (_Float16)ogv;
        hnew[ci] = (_Float16)(ogv * ftanh_(cnew));
      }
    }
  } else {
#pragma unroll
    for (int m = 0; m < 2; ++m)
#pragma unroll
      for (int n = 0; n < 4; ++n) {
        int uu = nBase + n * 16 + c_;
        float bn = brnn[uu];
#pragma unroll
        for (int r = 0; r < 4; ++r) {
          int b = mBase + w * 32 + m * 16 + rg * 4 + r;
          rout[(size_t)b * 512 + uu] = (_Float16)ftanh_(acc[m][n][r] + bn);
        }
      }
  }
}

// Fused dispatch: y < yRnn -> RNN 128x64 tiles (n = y*64; dispatched first);
// y >= yRnn -> LSTM 128x128 tiles (n = (y-yRnn)*128). Both read h(t-1).
__global__ __launch_bounds__(256, 3) void fused_step(
    const _Float16* __restrict__ hprev, _Float16* __restrict__ hnew,
    const _Float16* __restrict__ rin, _Float16* __restrict__ rot,
    const _Float16* __restrict__ WrT, const _Float16* __restrict__ W2T,
    const float* __restrict__ x, const float* __restrict__ Kp,
    const float* __restrict__ bp, _Float16* __restrict__ cbuf,
    _Float16* __restrict__ og, const float* __restrict__ brnn,
    const int* __restrict__ idxL, const int* __restrict__ MpadP,
    int t, int yRnn) {
  __shared__ __align__(16) _Float16 Ab[3][4096];
  __shared__ __align__(16) _Float16 Bb[3][4096];
  if ((int)blockIdx.y < yRnn) {
    gemm_tile<1>(Ab, Bb, hprev, rin, W2T, nullptr, nullptr, nullptr, nullptr,
                 nullptr, nullptr, brnn, rot, nullptr,
                 blockIdx.x * 128, blockIdx.y * 64, t);
  } else {
    if ((int)blockIdx.x * 128 >= *MpadP) return;
    gemm_tile<0>(Ab, Bb, hprev, nullptr, WrT, x, Kp, bp, cbuf, og, hnew,
                 nullptr, nullptr, idxL,
                 blockIdx.x * 128, ((int)blockIdx.y - yRnn) * 128, t);
  }
}

__global__ __launch_bounds__(256, 3) void rnn_tail(
    const _Float16* __restrict__ h, const _Float16* __restrict__ rin,
    const _Float16* __restrict__ W2T, const float* __restrict__ brnn,
    _Float16* __restrict__ rot) {
  __shared__ __align__(16) _Float16 Ab[3][4096];
  __shared__ __align__(16) _Float16 Bb[3][4096];
  gemm_tile<1>(Ab, Bb, h, rin, W2T, nullptr, nullptr, nullptr, nullptr,
               nullptr, nullptr, brnn, rot, nullptr,
               blockIdx.x * 128, blockIdx.y * 64, 0);
}

// unlearned rows only: h[b][u] = og[orow[b]][u] * tanh(c[b][u])
__global__ void gather_h(const _Float16* __restrict__ og, const _Float16* __restrict__ cbuf,
                         const int* __restrict__ orow, const int* __restrict__ idxU,
                         _Float16* __restrict__ h) {
  int g = blockIdx.x * 256 + threadIdx.x;
  int b = idxU[g >> 6];
  if (b < 0) return;
  int u0 = (g & 63) << 3;
  int src = orow[b];
  f16x8 ov = *(const f16x8*)(og + (size_t)src * 512 + u0);
  f16x8 cv = *(const f16x8*)(cbuf + (size_t)b * 512 + u0);
  f16x8 hv;
#pragma unroll
  for (int j = 0; j < 8; ++j) hv[j] = (_Float16)((float)ov[j] * ftanh_((float)cv[j]));
  *(f16x8*)(h + (size_t)b * 512 + u0) = hv;
}

// out[b] = dot(r[b], wv) + c0  (one wave per row), fp32 output
__global__ void final_fc(const _Float16* __restrict__ r, const float* __restrict__ wv,
                         float* __restrict__ out) {
  int gw = (blockIdx.x * 256 + threadIdx.x) >> 6;
  int l = threadIdx.x & 63;
  f16x8 rv = *(const f16x8*)(r + (size_t)gw * 512 + l * 8);
  const float4* wp = (const float4*)(wv + l * 8);
  float4 w0 = wp[0], w1 = wp[1];
  float wf[8] = {w0.x, w0.y, w0.z, w0.w, w1.x, w1.y, w1.z, w1.w};
  float s = 0.0f;
#pragma unroll
  for (int j = 0; j < 8; ++j) s += (float)rv[j] * wf[j];
  for (int o = 32; o; o >>= 1) s += __shfl_down(s, o);
  if (l == 0) out[gw] = s + wv[512];
}

extern "C" void kernel_launch(void* const* d_in, const int* in_sizes, int n_in,
                              void* d_out, int out_size, void* d_ws, size_t ws_size,
                              hipStream_t stream) {
  const float* x    = (const float*)d_in[0];
  const int*   lt   = (const int*)d_in[1];
  const float* kern = (const float*)d_in[2];
  const float* Wr   = (const float*)d_in[3];
  const float* bias = (const float*)d_in[4];
  const float* wrnn = (const float*)d_in[5];
  const float* urnn = (const float*)d_in[6];
  const float* brnn = (const float*)d_in[7];
  const float* wfc  = (const float*)d_in[8];
  const float* bfc  = (const float*)d_in[9];
  const float* wout = (const float*)d_in[10];
  const float* bout = (const float*)d_in[11];

  char* ws = (char*)d_ws;
  size_t off = 0;
  auto alloc = [&](size_t bytes) {
    void* p = ws + off;
    off = (off + bytes + 255) & ~(size_t)255;
    return p;
  };
  int*      orow = (int*)alloc((size_t)T_ * B_ * 4);
  int*      idxL = (int*)alloc((size_t)T_ * B_ * 4);
  int*      idxU = (int*)alloc((size_t)T_ * B_ * 4);
  int*      Mpad = (int*)alloc(T_ * 4);
  _Float16* cbuf = (_Float16*)alloc((size_t)B_ * U_ * 2);
  _Float16* h0   = (_Float16*)alloc((size_t)B_ * U_ * 2);
  _Float16* h1   = (_Float16*)alloc((size_t)B_ * U_ * 2);
  _Float16* r0   = (_Float16*)alloc((size_t)B_ * U_ * 2);
  _Float16* r1   = (_Float16*)alloc((size_t)B_ * U_ * 2);
  _Float16* og   = (_Float16*)alloc((size_t)B_ * U_ * 2);
  _Float16* WrT  = (_Float16*)alloc((size_t)2048 * 512 * 2);
  _Float16* W2T  = (_Float16*)alloc((size_t)512 * 1024 * 2);
  float*    Kp   = (float*)alloc(3 * 2048 * 4);
  float*    bp   = (float*)alloc(2048 * 4);
  float*    wv   = (float*)alloc(516 * 4);

  hipMemsetAsync(cbuf, 0, (size_t)B_ * U_ * 2, stream);
  hipMemsetAsync(h0, 0, (size_t)B_ * U_ * 2, stream);
  hipMemsetAsync(r0, 0, (size_t)B_ * U_ * 2, stream);

  prep_weights<<<4096, 256, 0, stream>>>(Wr, wrnn, urnn, kern, bias, WrT, W2T, Kp, bp);
  prep_wv<<<2, 256, 0, stream>>>(wfc, bfc, wout, bout, wv);
  prep_mask<<<T_, 1024, 0, stream>>>(lt, orow, idxL, idxU, Mpad);

  _Float16* hbuf[2] = {h0, h1};
  _Float16* rin = r0;
  _Float16* rot = r1;
  // step t reads hbuf[t&1] (= h(t-1)), writes hbuf[(t+1)&1] (= h(t))
  fused_step<<<dim3(64, 16), 256, 0, stream>>>(h0, h1, nullptr, nullptr, WrT, W2T, x,
                                               Kp, bp, cbuf, og, brnn, idxL, Mpad, 0, 0);
  gather_h<<<2048, 256, 0, stream>>>(og, cbuf, orow, idxU, h1);
  for (int t = 1; t < T_; ++t) {
    _Float16* hp = hbuf[t & 1];
    _Float16* hn = hbuf[(t + 1) & 1];
    // y 0..7: RNN 128x64 tiles (512 blocks, dispatched first);
    // y 8..23: LSTM 128x128 tiles.
    fused_step<<<dim3(64, 24), 256, 0, stream>>>(hp, hn, rin, rot, WrT, W2T, x, Kp, bp,
                                                 cbuf, og, brnn,
                                                 idxL + (size_t)t * B_, Mpad + t, t, 8);
    _Float16* tmp = rin; rin = rot; rot = tmp;  // rin now holds r(t-1)
    gather_h<<<2048, 256, 0, stream>>>(og, cbuf, orow + (size_t)t * B_,
                                       idxU + (size_t)t * B_, hn);
  }
  // tail: r(20) from h(20) in hbuf[T_&1], r(19) = rin
  rnn_tail<<<dim3(64, 8), 256, 0, stream>>>(hbuf[T_ & 1], rin, W2T, brnn, rot);
  final_fc<<<2048, 256, 0, stream>>>(rot, wv, (float*)d_out);
}